// Round 5
// baseline (148.289 us; speedup 1.0000x reference)
//
#include <hip/hip_runtime.h>

// WassersteinLoss: out = scale * sum_{b,c,t} |a-b| * (T - t)
// R4: width ablation. All prior rounds (vector x4, nt x4, LDS-DMA x4) pinned
// at ~5-6.7 B/cyc/CU read. Hypothesis: TCP miss pipeline has limited
// per-instruction line parallelism -> narrow dword loads (4 lines/instr,
// 4x instrs) expose more independent miss batches. Fully static: 8192
// blocks x 256 thr = 2M threads, exactly 8 elems/thread/array, batch-8 nt
// dword loads all in flight before consumption.

#define T_MASK 8191
#define T_DIMF 8192.0f
#define BATCH 8

__global__ __launch_bounds__(256)
void wl_partial_kernel(const float* __restrict__ a,
                       const float* __restrict__ b,
                       float* __restrict__ partial,
                       int n) {
    const int tid = blockIdx.x * blockDim.x + threadIdx.x;
    const int stride = gridDim.x * blockDim.x;

    float acc0 = 0.0f, acc1 = 0.0f, acc2 = 0.0f, acc3 = 0.0f;
    int v = tid;

    for (; v + (BATCH - 1) * stride < n; v += BATCH * stride) {
        float xa[BATCH], xb[BATCH];
        // all 16 dword loads issued before any use
        #pragma unroll
        for (int i = 0; i < BATCH; ++i)
            xa[i] = __builtin_nontemporal_load(&a[v + i * stride]);
        #pragma unroll
        for (int i = 0; i < BATCH; ++i)
            xb[i] = __builtin_nontemporal_load(&b[v + i * stride]);
        #pragma unroll
        for (int i = 0; i < BATCH; ++i) {
            int e = v + i * stride;
            float w = T_DIMF - (float)(e & T_MASK);
            float s = w * fabsf(xa[i] - xb[i]);
            if ((i & 3) == 0) acc0 += s;
            else if ((i & 3) == 1) acc1 += s;
            else if ((i & 3) == 2) acc2 += s;
            else acc3 += s;
        }
    }
    // tail (empty for shipped shape: 8192*256*8 == n)
    for (; v < n; v += stride) {
        float w = T_DIMF - (float)(v & T_MASK);
        acc0 += w * fabsf(__builtin_nontemporal_load(&a[v]) -
                          __builtin_nontemporal_load(&b[v]));
    }

    float acc = (acc0 + acc1) + (acc2 + acc3);

    #pragma unroll
    for (int off = 32; off > 0; off >>= 1)
        acc += __shfl_down(acc, off, 64);

    __shared__ float wave_sums[4];
    int lane = threadIdx.x & 63;
    int wave = threadIdx.x >> 6;
    if (lane == 0) wave_sums[wave] = acc;
    __syncthreads();

    if (threadIdx.x == 0)
        partial[blockIdx.x] = wave_sums[0] + wave_sums[1] + wave_sums[2] + wave_sums[3];
}

__global__ __launch_bounds__(256)
void wl_final_kernel(const float* __restrict__ partial, int n,
                     float* __restrict__ out, float scale) {
    float acc = 0.0f;
    for (int i = threadIdx.x; i < n; i += 256)
        acc += partial[i];

    #pragma unroll
    for (int off = 32; off > 0; off >>= 1)
        acc += __shfl_down(acc, off, 64);

    __shared__ float wave_sums[4];
    int lane = threadIdx.x & 63;
    int wave = threadIdx.x >> 6;
    if (lane == 0) wave_sums[wave] = acc;
    __syncthreads();

    if (threadIdx.x == 0)
        out[0] = (wave_sums[0] + wave_sums[1] + wave_sums[2] + wave_sums[3]) * scale;
}

extern "C" void kernel_launch(void* const* d_in, const int* in_sizes, int n_in,
                              void* d_out, int out_size, void* d_ws, size_t ws_size,
                              hipStream_t stream) {
    const float* a = (const float*)d_in[0];
    const float* b = (const float*)d_in[1];
    float* out = (float*)d_out;
    float* partial = (float*)d_ws;   // 8192 floats = 32 KB scratch

    int n = in_sizes[0];             // 16,777,216

    const long long T = 8192;
    const long long C = 64;
    const long long B = (long long)n / (C * T);
    float scale = (float)(2.0 / ((double)T * (double)C * (double)(T + 1) * (double)B));

    const int threads = 256;
    const int blocks = 8192;         // 2M threads; exactly one batch-8 iter each
    wl_partial_kernel<<<blocks, threads, 0, stream>>>(a, b, partial, n);
    wl_final_kernel<<<1, threads, 0, stream>>>(partial, blocks, out, scale);
}

// Round 6
// 130.520 us; speedup vs baseline: 1.1361x; 1.1361x over previous
//
#include <hip/hip_runtime.h>

// WassersteinLoss: out = scale * sum_{b,c,t} |a-b| * (T - t)
// R5: dual-path read test. Hypothesis: TCP vector-load miss pool and
// global_load_lds DMA queue are separate outstanding-request pools; driving
// both concurrently (a via nt vector loads, b via LDS-DMA, both in flight
// before the barrier) doubles per-CU in-flight miss capacity.
// 2048 blocks x 256 thr, 8 resident/CU (16 KB LDS), 2 iters/block,
// 8 KB in flight per wave per path per iteration.

#define T_MASK 8191
#define T_DIMF 8192.0f

#define FLOATS_PER_BLOCK 8192
#define CHUNK_FLOATS 4096          // 16 KB LDS chunk of b per iteration
#define NITER (FLOATS_PER_BLOCK / CHUNK_FLOATS)   // 2

typedef float vfloat4 __attribute__((ext_vector_type(4)));

__device__ __forceinline__ void load_lds16(const float* g, float* l) {
    __builtin_amdgcn_global_load_lds(
        (const __attribute__((address_space(1))) void*)g,
        (__attribute__((address_space(3))) void*)l,
        16 /*bytes per lane*/, 0 /*offset*/, 0 /*aux*/);
}

__global__ __launch_bounds__(256)
void wl_partial_kernel(const float* __restrict__ a,
                       const float* __restrict__ b,
                       float* __restrict__ partial) {
    __shared__ float ldsB[CHUNK_FLOATS];

    const int tid  = threadIdx.x;
    const int lane = tid & 63;
    const int wave = tid >> 6;                   // 0..3
    const int blockBase = blockIdx.x * FLOATS_PER_BLOCK;

    float acc = 0.0f;

    for (int it = 0; it < NITER; ++it) {
        const int chunkBase = blockBase + it * CHUNK_FLOATS;

        // Path 1: DMA b-chunk into LDS (4 instrs/wave, 4 KB/wave in flight).
        // LDS dest is wave-uniform base; HW scatters lane i at base+16*i.
        #pragma unroll
        for (int s = 0; s < 4; ++s) {
            const int seg = wave * 1024 + s * 256;       // float offset (uniform)
            load_lds16(b + chunkBase + seg + lane * 4, &ldsB[seg]);
        }

        // Path 2: nt vector loads of the matching a-chunk into VGPRs
        // (4 instrs/thread, issued while the DMA is still in flight).
        vfloat4 xa[4];
        const vfloat4* a4 = (const vfloat4*)a;
        const int c4 = chunkBase >> 2;                   // float4 base of chunk
        #pragma unroll
        for (int k = 0; k < 4; ++k)
            xa[k] = __builtin_nontemporal_load(&a4[c4 + tid + k * 256]);

        __syncthreads();   // vmcnt(0) drain: both paths complete

        #pragma unroll
        for (int k = 0; k < 4; ++k) {
            const int f4 = tid + k * 256;                // float4 index in chunk
            vfloat4 y = ((const vfloat4*)ldsB)[f4];
            const int g = chunkBase + f4 * 4;            // global float idx of .x
            float w = T_DIMF - (float)(g & T_MASK);      // 4|T so no row wrap
            float d0 = fabsf(xa[k].x - y.x);
            float d1 = fabsf(xa[k].y - y.y);
            float d2 = fabsf(xa[k].z - y.z);
            float d3 = fabsf(xa[k].w - y.w);
            acc += w * (d0 + d1 + d2 + d3) - (d1 + 2.0f * d2 + 3.0f * d3);
        }
        __syncthreads();   // protect ldsB before next iteration's DMA
    }

    // wave-64 shuffle reduction
    #pragma unroll
    for (int off = 32; off > 0; off >>= 1)
        acc += __shfl_down(acc, off, 64);

    __shared__ float wave_sums[4];
    if (lane == 0) wave_sums[wave] = acc;
    __syncthreads();

    if (tid == 0)
        partial[blockIdx.x] = wave_sums[0] + wave_sums[1] + wave_sums[2] + wave_sums[3];
}

__global__ __launch_bounds__(256)
void wl_final_kernel(const float* __restrict__ partial, int n,
                     float* __restrict__ out, float scale) {
    float acc = 0.0f;
    for (int i = threadIdx.x; i < n; i += 256)
        acc += partial[i];

    #pragma unroll
    for (int off = 32; off > 0; off >>= 1)
        acc += __shfl_down(acc, off, 64);

    __shared__ float wave_sums[4];
    int lane = threadIdx.x & 63;
    int wave = threadIdx.x >> 6;
    if (lane == 0) wave_sums[wave] = acc;
    __syncthreads();

    if (threadIdx.x == 0)
        out[0] = (wave_sums[0] + wave_sums[1] + wave_sums[2] + wave_sums[3]) * scale;
}

extern "C" void kernel_launch(void* const* d_in, const int* in_sizes, int n_in,
                              void* d_out, int out_size, void* d_ws, size_t ws_size,
                              hipStream_t stream) {
    const float* a = (const float*)d_in[0];
    const float* b = (const float*)d_in[1];
    float* out = (float*)d_out;
    float* partial = (float*)d_ws;   // 2048 floats = 8 KB scratch

    int n = in_sizes[0];             // 16,777,216
    int blocks = n / FLOATS_PER_BLOCK;   // 2048

    const long long T = 8192;
    const long long C = 64;
    const long long B = (long long)n / (C * T);
    float scale = (float)(2.0 / ((double)T * (double)C * (double)(T + 1) * (double)B));

    wl_partial_kernel<<<blocks, 256, 0, stream>>>(a, b, partial);
    wl_final_kernel<<<1, 256, 0, stream>>>(partial, blocks, out, scale);
}